// Round 2
// 1071.662 us; speedup vs baseline: 1.1249x; 1.1249x over previous
//
#include <hip/hip_runtime.h>
#include <hip/hip_bf16.h>
#include <stdint.h>

// Decoder: B=256, H=512, S=512, O=2.
// Pipeline:
//  zero -> prep_misc (weight casts, embedding) -> transpose_cast (enc -> bf16 [b][s][k])
//  -> gemm gx, gh -> GRU gates (writes hidden out) -> gemm hc
//  -> big_gemm K1 (scores = sum_h v*tanh(Wa@st + Wb@dy + hc))  [K=1024 fused]
//  -> softmax -> context -> gemm cd
//  -> big_gemm K4 (outputs = sum_h dec_v*tanh(Wd1@st + cd))

typedef __attribute__((ext_vector_type(8))) short short8;
typedef __attribute__((ext_vector_type(4))) float f32x4;

__device__ __forceinline__ unsigned short f2bf(float f) {
    __hip_bfloat16 h = __float2bfloat16(f);
    return *reinterpret_cast<unsigned short*>(&h);
}
__device__ __forceinline__ float sigm(float x) { return 1.f / (1.f + __expf(-x)); }
__device__ __forceinline__ float tanh_fast(float x) {
    float e = __expf(2.f * x);
    return 1.f - 2.f / (e + 1.f);
}

// ---------------- tiny utility kernels ----------------
__global__ void zero_kernel(float* scores, float* outp) {
    int i = blockIdx.x * 256 + threadIdx.x;
    if (i < 131072) { scores[i] = 0.f; outp[i] = 0.f; }
}

__global__ void fill_sentinel(float* p, int n) {
    int i = blockIdx.x * 256 + threadIdx.x;
    if (i < n) p[i] = 12345.0f;
}

// weight casts + embedding + h cast. Flat-id ladder. 3,145,728 elems -> 12288 blocks.
__global__ void prep_misc(const float* __restrict__ attn_W, const float* __restrict__ dec_W,
                          const float* __restrict__ gWih, const float* __restrict__ gWhh,
                          const float* __restrict__ lo, const float* __restrict__ embW,
                          const float* __restrict__ embb, const float* __restrict__ lh,
                          unsigned short* Wab, unsigned short* Wd1,
                          unsigned short* Wih, unsigned short* Whh,
                          unsigned short* Wc, unsigned short* Wd2,
                          unsigned short* xbf, unsigned short* hbf) {
    int i = blockIdx.x * 256 + threadIdx.x;
    if (i < 786432) { Wih[i] = f2bf(gWih[i]); return; } i -= 786432;
    if (i < 786432) { Whh[i] = f2bf(gWhh[i]); return; } i -= 786432;
    if (i < 524288) { int m = i >> 10, k = i & 1023; Wab[i] = f2bf(attn_W[m * 1536 + k]); return; } i -= 524288;
    if (i < 262144) { int m = i >> 9, k = i & 511; Wc[i]  = f2bf(attn_W[m * 1536 + 1024 + k]); return; } i -= 262144;
    if (i < 262144) { int m = i >> 9, k = i & 511; Wd1[i] = f2bf(dec_W[m * 1024 + k]); return; } i -= 262144;
    if (i < 262144) { int m = i >> 9, k = i & 511; Wd2[i] = f2bf(dec_W[m * 1024 + 512 + k]); return; } i -= 262144;
    if (i < 131072) { int b = i >> 9, j = i & 511;
        float v = lo[b * 2] * embW[j * 2] + lo[b * 2 + 1] * embW[j * 2 + 1] + embb[j];
        xbf[i] = f2bf(v); return; } i -= 131072;
    if (i < 131072) { hbf[i] = f2bf(lh[i]); return; }
}

// enc [b][k][s] fp32 -> [b][s][k] bf16, LDS-tiled 64x64 transpose.
// Phase 1: float4 loads coalesced along s -> LDS [64][65] fp32 (pad 65 -> 2-way bank alias, free).
// Phase 2: gather 8 fp32 along k (2-way alias, free), cvt bf16, store contiguous 16B short8.
// Lanes 0..7 of phase-2 cover 128 contiguous output bytes -> full 64B-line coverage, no RMW.
__global__ __launch_bounds__(256) void transpose_cast(
    const float* __restrict__ st, const float* __restrict__ dy,
    unsigned short* __restrict__ stT, unsigned short* __restrict__ dyT) {
    __shared__ float tile[64 * 65];
    const int b = blockIdx.y;
    const int tx = blockIdx.x;                 // 0..63
    const int k0 = (tx & 7) * 64, s0 = (tx >> 3) * 64;
    const float* src = (blockIdx.z ? dy : st) + (size_t)b * 262144;
    unsigned short* dst = (blockIdx.z ? dyT : stT) + (size_t)b * 262144;
    const int t = threadIdx.x;
    const int sl = (t & 15) * 4, kl = t >> 4;  // kl 0..15
#pragma unroll
    for (int j = 0; j < 4; j++) {
        int k = kl + 16 * j;
        f32x4 v = *(const f32x4*)(src + (size_t)(k0 + k) * 512 + s0 + sl);
        tile[k * 65 + sl + 0] = v[0];
        tile[k * 65 + sl + 1] = v[1];
        tile[k * 65 + sl + 2] = v[2];
        tile[k * 65 + sl + 3] = v[3];
    }
    __syncthreads();
#pragma unroll
    for (int i = 0; i < 2; i++) {
        int idx = t + i * 256;
        int s = idx >> 3, kg = idx & 7;
        short8 o;
#pragma unroll
        for (int e = 0; e < 8; e++)
            o[e] = (short)f2bf(tile[(kg * 8 + e) * 65 + s]);
        *(short8*)(dst + (size_t)(s0 + s) * 512 + k0 + kg * 8) = o;
    }
}

// ---------------- small LDS-free MFMA GEMM ----------------
// D[n*ldd + m] = sum_k A[m][k]*B[n][k], K=512, N=256 fixed. 64x64 tile per wave.
__global__ __launch_bounds__(256) void gemm_nt_small(
    const unsigned short* __restrict__ A, int lda,
    const unsigned short* __restrict__ Bm, int ldb,
    float* __restrict__ D, int ldd, int Mdim) {
    int w = blockIdx.x * 4 + (threadIdx.x >> 6);
    int lane = threadIdx.x & 63;
    int mb = w >> 2, nbk = w & 3;   // N=256 -> 4 n-blocks
    if (mb >= (Mdim >> 6)) return;
    int m0 = mb * 64, n0 = nbk * 64;
    int col = lane & 15, quad = lane >> 4;
    f32x4 acc[4][4] = {};
    for (int k0 = 0; k0 < 512; k0 += 32) {
        short8 af[4], bfr[4];
#pragma unroll
        for (int t = 0; t < 4; t++)
            af[t] = *(const short8*)(A + (size_t)(m0 + t * 16 + col) * lda + k0 + quad * 8);
#pragma unroll
        for (int t = 0; t < 4; t++)
            bfr[t] = *(const short8*)(Bm + (size_t)(n0 + t * 16 + col) * ldb + k0 + quad * 8);
#pragma unroll
        for (int mt = 0; mt < 4; mt++)
#pragma unroll
            for (int nt = 0; nt < 4; nt++)
                acc[mt][nt] = __builtin_amdgcn_mfma_f32_16x16x32_bf16(af[mt], bfr[nt], acc[mt][nt], 0, 0, 0);
    }
#pragma unroll
    for (int mt = 0; mt < 4; mt++)
#pragma unroll
        for (int nt = 0; nt < 4; nt++) {
            int n = n0 + nt * 16 + col;
            int m = m0 + mt * 16 + quad * 4;
#pragma unroll
            for (int r = 0; r < 4; r++)
                D[(size_t)n * ldd + m + r] = acc[mt][nt][r];
        }
}

// ---------------- GRU gate fusion ----------------
__global__ void gru_gates(const float* __restrict__ gx, const float* __restrict__ gh,
                          const float* __restrict__ lh,
                          const float* __restrict__ bih, const float* __restrict__ bhh,
                          float* __restrict__ hidden_out, unsigned short* __restrict__ hnbf) {
    int i = blockIdx.x * 256 + threadIdx.x;  // 131072
    int b = i >> 9, j = i & 511;
    float xr = gx[b * 1536 + j] + bih[j];
    float xz = gx[b * 1536 + 512 + j] + bih[512 + j];
    float xn = gx[b * 1536 + 1024 + j] + bih[1024 + j];
    float hr = gh[b * 1536 + j] + bhh[j];
    float hz = gh[b * 1536 + 512 + j] + bhh[512 + j];
    float hn = gh[b * 1536 + 1024 + j] + bhh[1024 + j];
    float r = sigm(xr + hr), z = sigm(xz + hz);
    float n = tanh_fast(xn + r * hn);
    float h = (1.f - z) * n + z * lh[i];
    hidden_out[i] = h;
    hnbf[i] = f2bf(h);
}

// ---------------- big fused GEMM + tanh + v-dot reduce ----------------
// D[h][s] = sum_k A[h][k]*Benc[b][s][k] ; out[b][s] += sum_h vvec[h]*tanh(D + bias[b][h])
// m97-style: 128x128 block (2x2 waves of 64x64), BK=64, global_load_lds staging,
// XOR source-swizzle (p = q ^ (row&7)) -> 2-way (free) LDS bank aliasing on frag reads.
__global__ __launch_bounds__(256) void big_gemm(
    const unsigned short* __restrict__ A, int lda,
    const unsigned short* __restrict__ B1, const unsigned short* __restrict__ B2,
    int itersB1, int iters,
    const float* __restrict__ bias, const float* __restrict__ vvec,
    float* __restrict__ outAcc) {
    __shared__ __align__(16) unsigned short lds[16384];  // 16KB A + 16KB B
    const int b = blockIdx.z;
    const int m0 = blockIdx.x * 128, n0 = blockIdx.y * 128;
    const int tid = threadIdx.x, lane = tid & 63, w = tid >> 6;
    const int wi = w >> 1, wj = w & 1;
    const int col = lane & 15, quad = lane >> 4;
    f32x4 acc[4][4] = {};

    for (int it = 0; it < iters; ++it) {
        const unsigned short* Bs; int kb;
        if (it < itersB1) { Bs = B1; kb = it * 64; } else { Bs = B2; kb = (it - itersB1) * 64; }
        const int ka = it * 64;
        __syncthreads();  // previous iter's LDS reads complete
        // stage A tile [128 rows x 64 k] bf16 = 16KB
#pragma unroll
        for (int i = 0; i < 4; i++) {
            int sb = w * 256 + i * 64;
            int slot = sb + lane;
            int row = slot >> 3, p = slot & 7, q = p ^ (row & 7);
            const unsigned short* g = A + (size_t)(m0 + row) * lda + (ka + q * 8);
            __builtin_amdgcn_global_load_lds((const __attribute__((address_space(1))) void*)g,
                                             (__attribute__((address_space(3))) void*)(&lds[sb * 8]), 16, 0, 0);
        }
        const unsigned short* Bbase = Bs + ((size_t)b * 512 + n0) * 512 + kb;
#pragma unroll
        for (int i = 0; i < 4; i++) {
            int sb = w * 256 + i * 64;
            int slot = sb + lane;
            int row = slot >> 3, p = slot & 7, q = p ^ (row & 7);
            const unsigned short* g = Bbase + (size_t)row * 512 + q * 8;
            __builtin_amdgcn_global_load_lds((const __attribute__((address_space(1))) void*)g,
                                             (__attribute__((address_space(3))) void*)(&lds[8192 + sb * 8]), 16, 0, 0);
        }
        asm volatile("s_waitcnt vmcnt(0)" ::: "memory");
        __syncthreads();
#pragma unroll
        for (int ss = 0; ss < 2; ++ss) {
            short8 af[4], bfv[4];
#pragma unroll
            for (int t = 0; t < 4; t++) {
                int q = ss * 4 + quad;
                int m_loc = wi * 64 + t * 16 + col;
                int pa = q ^ (m_loc & 7);
                af[t] = *(const short8*)&lds[(m_loc * 8 + pa) * 8];
                int n_loc = wj * 64 + t * 16 + col;
                int pb = q ^ (n_loc & 7);
                bfv[t] = *(const short8*)&lds[8192 + (n_loc * 8 + pb) * 8];
            }
#pragma unroll
            for (int mt = 0; mt < 4; mt++)
#pragma unroll
                for (int nt = 0; nt < 4; nt++)
                    acc[mt][nt] = __builtin_amdgcn_mfma_f32_16x16x32_bf16(af[mt], bfv[nt], acc[mt][nt], 0, 0, 0);
        }
    }
    // epilogue: tanh(acc + bias[b][h]) * vvec[h], reduce over the block's 128 h
    f32x4 bi[4], vv[4];
#pragma unroll
    for (int mt = 0; mt < 4; ++mt) {
        int h = m0 + wi * 64 + mt * 16 + quad * 4;
        bi[mt] = *(const f32x4*)&bias[b * 512 + h];
        vv[mt] = *(const f32x4*)&vvec[h];
    }
#pragma unroll
    for (int nt = 0; nt < 4; ++nt) {
        float part = 0.f;
#pragma unroll
        for (int mt = 0; mt < 4; ++mt)
#pragma unroll
            for (int r = 0; r < 4; r++)
                part += tanh_fast(acc[mt][nt][r] + bi[mt][r]) * vv[mt][r];
        part += __shfl_down(part, 32);
        part += __shfl_down(part, 16);
        if (lane < 16) {
            int s = n0 + wj * 64 + nt * 16 + col;
            atomicAdd(&outAcc[b * 512 + s], part);
        }
    }
}

// ---------------- softmax over s (per b) ----------------
__global__ void softmax512(const float* __restrict__ sc, float* __restrict__ attn) {
    int b = blockIdx.x, t = threadIdx.x, lane = t & 63, w = t >> 6;
    __shared__ float sm[4];
    float v0 = sc[b * 512 + t], v1 = sc[b * 512 + 256 + t];
    float m = fmaxf(v0, v1);
    for (int d = 32; d; d >>= 1) m = fmaxf(m, __shfl_xor(m, d));
    if (lane == 0) sm[w] = m;
    __syncthreads();
    m = fmaxf(fmaxf(sm[0], sm[1]), fmaxf(sm[2], sm[3]));
    float e0 = __expf(v0 - m), e1 = __expf(v1 - m);
    float s = e0 + e1;
    for (int d = 32; d; d >>= 1) s += __shfl_xor(s, d);
    __syncthreads();
    if (lane == 0) sm[w] = s;
    __syncthreads();
    s = sm[0] + sm[1] + sm[2] + sm[3];
    float inv = 1.f / s;
    attn[b * 512 + t] = e0 * inv;
    attn[b * 512 + 256 + t] = e1 * inv;
}

// ---------------- context = attn @ static^T (per b) ----------------
__global__ __launch_bounds__(256) void context_kernel(
    const float* __restrict__ st, const float* __restrict__ attn,
    float* __restrict__ ctx, unsigned short* __restrict__ ctxbf) {
    int b = blockIdx.y, hq = blockIdx.x;
    int lane = threadIdx.x & 63, w = threadIdx.x >> 6;
    const float* ap = attn + b * 512 + lane * 8;
    f32x4 a0 = *(const f32x4*)ap, a1 = *(const f32x4*)(ap + 4);
    for (int i = 0; i < 32; i++) {
        int h = hq * 128 + w * 32 + i;
        const float* row = st + ((size_t)b * 512 + h) * 512 + lane * 8;
        f32x4 r0 = *(const f32x4*)row, r1 = *(const f32x4*)(row + 4);
        float sum = r0[0] * a0[0] + r0[1] * a0[1] + r0[2] * a0[2] + r0[3] * a0[3]
                  + r1[0] * a1[0] + r1[1] * a1[1] + r1[2] * a1[2] + r1[3] * a1[3];
#pragma unroll
        for (int d = 32; d; d >>= 1) sum += __shfl_down(sum, d);
        if (lane == 0) { ctx[b * 512 + h] = sum; ctxbf[b * 512 + h] = f2bf(sum); }
    }
}

extern "C" void kernel_launch(void* const* d_in, const int* in_sizes, int n_in,
                              void* d_out, int out_size, void* d_ws, size_t ws_size,
                              hipStream_t stream) {
    const float* st    = (const float*)d_in[0];
    const float* dy    = (const float*)d_in[1];
    const float* lo    = (const float*)d_in[2];
    const float* lh    = (const float*)d_in[3];
    const float* embW  = (const float*)d_in[4];
    const float* embb  = (const float*)d_in[5];
    const float* gWih  = (const float*)d_in[6];
    const float* gWhh  = (const float*)d_in[7];
    const float* bih   = (const float*)d_in[8];
    const float* bhh   = (const float*)d_in[9];
    const float* attnv = (const float*)d_in[10];
    const float* attnW = (const float*)d_in[11];
    const float* decv  = (const float*)d_in[12];
    const float* decW  = (const float*)d_in[13];
    float* outp = (float*)d_out;            // [B,S] pointer logits
    float* hiddenp = outp + 131072;         // [1,B,H] new hidden

    const size_t NEED = 281018368ULL;
    if (ws_size < NEED) {
        fill_sentinel<<<1024, 256, 0, stream>>>((float*)d_out, out_size);
        return;
    }
    char* ws = (char*)d_ws;
    unsigned short* stT = (unsigned short*)(ws);
    unsigned short* dyT = (unsigned short*)(ws + 134217728);
    char* s0 = ws + 268435456;
    unsigned short* Wab  = (unsigned short*)(s0);
    unsigned short* Wd1  = (unsigned short*)(s0 + 1048576);
    unsigned short* Wih  = (unsigned short*)(s0 + 1572864);
    unsigned short* Whh  = (unsigned short*)(s0 + 3145728);
    unsigned short* Wc   = (unsigned short*)(s0 + 4718592);
    unsigned short* Wd2  = (unsigned short*)(s0 + 5242880);
    unsigned short* xbf  = (unsigned short*)(s0 + 5767168);
    unsigned short* hbf  = (unsigned short*)(s0 + 6029312);
    unsigned short* hnbf = (unsigned short*)(s0 + 6291456);
    unsigned short* ctxbf= (unsigned short*)(s0 + 6553600);
    float* gx     = (float*)(s0 + 6815744);
    float* gh     = (float*)(s0 + 8388608);
    float* hc     = (float*)(s0 + 9961472);
    float* cd     = (float*)(s0 + 10485760);
    float* scores = (float*)(s0 + 11010048);
    float* attn   = (float*)(s0 + 11534336);
    float* ctx    = (float*)(s0 + 12058624);

    zero_kernel<<<512, 256, 0, stream>>>(scores, outp);
    prep_misc<<<12288, 256, 0, stream>>>(attnW, decW, gWih, gWhh, lo, embW, embb, lh,
                                         Wab, Wd1, Wih, Whh, Wc, Wd2, xbf, hbf);
    transpose_cast<<<dim3(64, 256, 2), 256, 0, stream>>>(st, dy, stT, dyT);
    gemm_nt_small<<<24, 256, 0, stream>>>(Wih, 512, xbf, 512, gx, 1536, 1536);
    gemm_nt_small<<<24, 256, 0, stream>>>(Whh, 512, hbf, 512, gh, 1536, 1536);
    gru_gates<<<512, 256, 0, stream>>>(gx, gh, lh, bih, bhh, hiddenp, hnbf);
    gemm_nt_small<<<8, 256, 0, stream>>>(Wc, 512, hnbf, 512, hc, 512, 512);
    big_gemm<<<dim3(4, 4, 256), 256, 0, stream>>>(Wab, 1024, stT, dyT, 8, 16, hc, attnv, scores);
    softmax512<<<256, 256, 0, stream>>>(scores, attn);
    context_kernel<<<dim3(4, 256), 256, 0, stream>>>(st, attn, ctx, ctxbf);
    gemm_nt_small<<<8, 256, 0, stream>>>(Wd2, 512, ctxbf, 512, cd, 512, 512);
    big_gemm<<<dim3(4, 4, 256), 256, 0, stream>>>(Wd1, 512, stT, stT, 8, 8, cd, decv, outp);
}

// Round 3
// 1070.135 us; speedup vs baseline: 1.1265x; 1.0014x over previous
//
#include <hip/hip_runtime.h>
#include <hip/hip_bf16.h>
#include <stdint.h>

// Decoder: B=256, H=512, S=512, O=2.
// Pipeline:
//  zero -> prep_misc (weight casts, embedding) -> transpose_cast (enc -> bf16 [b][s][k])
//  -> gemm gx, gh -> GRU gates (writes hidden out) -> gemm hc
//  -> big_gemm K1 (scores = sum_h v*tanh(Wa@st + Wb@dy + hc))  [K=1024 fused]
//  -> softmax -> context -> gemm cd
//  -> big_gemm K4 (outputs = sum_h dec_v*tanh(Wd1@st + cd))

typedef __attribute__((ext_vector_type(8))) short short8;
typedef __attribute__((ext_vector_type(4))) float f32x4;

__device__ __forceinline__ unsigned short f2bf(float f) {
    __hip_bfloat16 h = __float2bfloat16(f);
    return *reinterpret_cast<unsigned short*>(&h);
}
__device__ __forceinline__ float sigm(float x) { return 1.f / (1.f + __expf(-x)); }
__device__ __forceinline__ float tanh_fast(float x) {
    float e = __expf(2.f * x);
    return 1.f - 2.f / (e + 1.f);
}

// ---------------- tiny utility kernels ----------------
__global__ void zero_kernel(float* scores, float* outp) {
    int i = blockIdx.x * 256 + threadIdx.x;
    if (i < 131072) { scores[i] = 0.f; outp[i] = 0.f; }
}

__global__ void fill_sentinel(float* p, int n) {
    int i = blockIdx.x * 256 + threadIdx.x;
    if (i < n) p[i] = 12345.0f;
}

// weight casts + embedding + h cast. Flat-id ladder. 3,145,728 elems -> 12288 blocks.
__global__ void prep_misc(const float* __restrict__ attn_W, const float* __restrict__ dec_W,
                          const float* __restrict__ gWih, const float* __restrict__ gWhh,
                          const float* __restrict__ lo, const float* __restrict__ embW,
                          const float* __restrict__ embb, const float* __restrict__ lh,
                          unsigned short* Wab, unsigned short* Wd1,
                          unsigned short* Wih, unsigned short* Whh,
                          unsigned short* Wc, unsigned short* Wd2,
                          unsigned short* xbf, unsigned short* hbf) {
    int i = blockIdx.x * 256 + threadIdx.x;
    if (i < 786432) { Wih[i] = f2bf(gWih[i]); return; } i -= 786432;
    if (i < 786432) { Whh[i] = f2bf(gWhh[i]); return; } i -= 786432;
    if (i < 524288) { int m = i >> 10, k = i & 1023; Wab[i] = f2bf(attn_W[m * 1536 + k]); return; } i -= 524288;
    if (i < 262144) { int m = i >> 9, k = i & 511; Wc[i]  = f2bf(attn_W[m * 1536 + 1024 + k]); return; } i -= 262144;
    if (i < 262144) { int m = i >> 9, k = i & 511; Wd1[i] = f2bf(dec_W[m * 1024 + k]); return; } i -= 262144;
    if (i < 262144) { int m = i >> 9, k = i & 511; Wd2[i] = f2bf(dec_W[m * 1024 + 512 + k]); return; } i -= 262144;
    if (i < 131072) { int b = i >> 9, j = i & 511;
        float v = lo[b * 2] * embW[j * 2] + lo[b * 2 + 1] * embW[j * 2 + 1] + embb[j];
        xbf[i] = f2bf(v); return; } i -= 131072;
    if (i < 131072) { hbf[i] = f2bf(lh[i]); return; }
}

// enc [b][k][s] fp32 -> [b][s][k] bf16, LDS-tiled 64x64 transpose.
// Phase 1: float4 loads coalesced along s -> LDS [64][65] fp32 (pad 65 -> 2-way bank alias, free).
// Phase 2: gather 8 fp32 along k (2-way alias, free), cvt bf16, store contiguous 16B short8.
// Lanes 0..7 of phase-2 cover 128 contiguous output bytes -> full 64B-line coverage, no RMW.
__global__ __launch_bounds__(256) void transpose_cast(
    const float* __restrict__ st, const float* __restrict__ dy,
    unsigned short* __restrict__ stT, unsigned short* __restrict__ dyT) {
    __shared__ float tile[64 * 65];
    const int b = blockIdx.y;
    const int tx = blockIdx.x;                 // 0..63
    const int k0 = (tx & 7) * 64, s0 = (tx >> 3) * 64;
    const float* src = (blockIdx.z ? dy : st) + (size_t)b * 262144;
    unsigned short* dst = (blockIdx.z ? dyT : stT) + (size_t)b * 262144;
    const int t = threadIdx.x;
    const int sl = (t & 15) * 4, kl = t >> 4;  // kl 0..15
#pragma unroll
    for (int j = 0; j < 4; j++) {
        int k = kl + 16 * j;
        f32x4 v = *(const f32x4*)(src + (size_t)(k0 + k) * 512 + s0 + sl);
        tile[k * 65 + sl + 0] = v[0];
        tile[k * 65 + sl + 1] = v[1];
        tile[k * 65 + sl + 2] = v[2];
        tile[k * 65 + sl + 3] = v[3];
    }
    __syncthreads();
#pragma unroll
    for (int i = 0; i < 2; i++) {
        int idx = t + i * 256;
        int s = idx >> 3, kg = idx & 7;
        short8 o;
#pragma unroll
        for (int e = 0; e < 8; e++)
            o[e] = (short)f2bf(tile[(kg * 8 + e) * 65 + s]);
        *(short8*)(dst + (size_t)(s0 + s) * 512 + k0 + kg * 8) = o;
    }
}

// ---------------- small LDS-free MFMA GEMM ----------------
// D[n*ldd + m] = sum_k A[m][k]*B[n][k], K=512, N=256 fixed. 64x64 tile per wave.
__global__ __launch_bounds__(256) void gemm_nt_small(
    const unsigned short* __restrict__ A, int lda,
    const unsigned short* __restrict__ Bm, int ldb,
    float* __restrict__ D, int ldd, int Mdim) {
    int w = blockIdx.x * 4 + (threadIdx.x >> 6);
    int lane = threadIdx.x & 63;
    int mb = w >> 2, nbk = w & 3;   // N=256 -> 4 n-blocks
    if (mb >= (Mdim >> 6)) return;
    int m0 = mb * 64, n0 = nbk * 64;
    int col = lane & 15, quad = lane >> 4;
    f32x4 acc[4][4] = {};
    for (int k0 = 0; k0 < 512; k0 += 32) {
        short8 af[4], bfr[4];
#pragma unroll
        for (int t = 0; t < 4; t++)
            af[t] = *(const short8*)(A + (size_t)(m0 + t * 16 + col) * lda + k0 + quad * 8);
#pragma unroll
        for (int t = 0; t < 4; t++)
            bfr[t] = *(const short8*)(Bm + (size_t)(n0 + t * 16 + col) * ldb + k0 + quad * 8);
#pragma unroll
        for (int mt = 0; mt < 4; mt++)
#pragma unroll
            for (int nt = 0; nt < 4; nt++)
                acc[mt][nt] = __builtin_amdgcn_mfma_f32_16x16x32_bf16(af[mt], bfr[nt], acc[mt][nt], 0, 0, 0);
    }
#pragma unroll
    for (int mt = 0; mt < 4; mt++)
#pragma unroll
        for (int nt = 0; nt < 4; nt++) {
            int n = n0 + nt * 16 + col;
            int m = m0 + mt * 16 + quad * 4;
#pragma unroll
            for (int r = 0; r < 4; r++)
                D[(size_t)n * ldd + m + r] = acc[mt][nt][r];
        }
}

// ---------------- GRU gate fusion ----------------
__global__ void gru_gates(const float* __restrict__ gx, const float* __restrict__ gh,
                          const float* __restrict__ lh,
                          const float* __restrict__ bih, const float* __restrict__ bhh,
                          float* __restrict__ hidden_out, unsigned short* __restrict__ hnbf) {
    int i = blockIdx.x * 256 + threadIdx.x;  // 131072
    int b = i >> 9, j = i & 511;
    float xr = gx[b * 1536 + j] + bih[j];
    float xz = gx[b * 1536 + 512 + j] + bih[512 + j];
    float xn = gx[b * 1536 + 1024 + j] + bih[1024 + j];
    float hr = gh[b * 1536 + j] + bhh[j];
    float hz = gh[b * 1536 + 512 + j] + bhh[512 + j];
    float hn = gh[b * 1536 + 1024 + j] + bhh[1024 + j];
    float r = sigm(xr + hr), z = sigm(xz + hz);
    float n = tanh_fast(xn + r * hn);
    float h = (1.f - z) * n + z * lh[i];
    hidden_out[i] = h;
    hnbf[i] = f2bf(h);
}

// ---------------- big fused GEMM + tanh + v-dot reduce ----------------
// D[h][s] = sum_k A[h][k]*Benc[b][s][k] ; out[b][s] += sum_h vvec[h]*tanh(D + bias[b][h])
// m97-style: 128x128 block (2x2 waves of 64x64), BK=64, global_load_lds staging,
// XOR source-swizzle (p = q ^ (row&7)) -> 2-way (free) LDS bank aliasing on frag reads.
// 1D grid 4096 + bijective XCD swizzle: XCD k owns lin in [k*512,(k+1)*512) = 32
// contiguous b-slices -> the 4 m-blocks sharing each B-tile run back-to-back on ONE
// XCD's L2 (B-tile refetch 4x -> ~1x), and the weight matrix stays L2-resident.
__global__ __launch_bounds__(256) void big_gemm(
    const unsigned short* __restrict__ A, int lda,
    const unsigned short* __restrict__ B1, const unsigned short* __restrict__ B2,
    int itersB1, int iters,
    const float* __restrict__ bias, const float* __restrict__ vvec,
    float* __restrict__ outAcc) {
    __shared__ __align__(16) unsigned short lds[16384];  // 16KB A + 16KB B
    const int wg0 = blockIdx.x;                       // 0..4095, XCD = wg0 % 8
    const int lin = (wg0 & 7) * 512 + (wg0 >> 3);     // bijective (4096 % 8 == 0)
    const int b = lin >> 4;
    const int m0 = (lin & 3) * 128, n0 = ((lin >> 2) & 3) * 128;
    const int tid = threadIdx.x, lane = tid & 63, w = tid >> 6;
    const int wi = w >> 1, wj = w & 1;
    const int col = lane & 15, quad = lane >> 4;
    f32x4 acc[4][4] = {};

    for (int it = 0; it < iters; ++it) {
        const unsigned short* Bs; int kb;
        if (it < itersB1) { Bs = B1; kb = it * 64; } else { Bs = B2; kb = (it - itersB1) * 64; }
        const int ka = it * 64;
        __syncthreads();  // previous iter's LDS reads complete
        // stage A tile [128 rows x 64 k] bf16 = 16KB
#pragma unroll
        for (int i = 0; i < 4; i++) {
            int sb = w * 256 + i * 64;
            int slot = sb + lane;
            int row = slot >> 3, p = slot & 7, q = p ^ (row & 7);
            const unsigned short* g = A + (size_t)(m0 + row) * lda + (ka + q * 8);
            __builtin_amdgcn_global_load_lds((const __attribute__((address_space(1))) void*)g,
                                             (__attribute__((address_space(3))) void*)(&lds[sb * 8]), 16, 0, 0);
        }
        const unsigned short* Bbase = Bs + ((size_t)b * 512 + n0) * 512 + kb;
#pragma unroll
        for (int i = 0; i < 4; i++) {
            int sb = w * 256 + i * 64;
            int slot = sb + lane;
            int row = slot >> 3, p = slot & 7, q = p ^ (row & 7);
            const unsigned short* g = Bbase + (size_t)row * 512 + q * 8;
            __builtin_amdgcn_global_load_lds((const __attribute__((address_space(1))) void*)g,
                                             (__attribute__((address_space(3))) void*)(&lds[8192 + sb * 8]), 16, 0, 0);
        }
        asm volatile("s_waitcnt vmcnt(0)" ::: "memory");
        __syncthreads();
#pragma unroll
        for (int ss = 0; ss < 2; ++ss) {
            short8 af[4], bfv[4];
#pragma unroll
            for (int t = 0; t < 4; t++) {
                int q = ss * 4 + quad;
                int m_loc = wi * 64 + t * 16 + col;
                int pa = q ^ (m_loc & 7);
                af[t] = *(const short8*)&lds[(m_loc * 8 + pa) * 8];
                int n_loc = wj * 64 + t * 16 + col;
                int pb = q ^ (n_loc & 7);
                bfv[t] = *(const short8*)&lds[8192 + (n_loc * 8 + pb) * 8];
            }
#pragma unroll
            for (int mt = 0; mt < 4; mt++)
#pragma unroll
                for (int nt = 0; nt < 4; nt++)
                    acc[mt][nt] = __builtin_amdgcn_mfma_f32_16x16x32_bf16(af[mt], bfv[nt], acc[mt][nt], 0, 0, 0);
        }
    }
    // epilogue: tanh(acc + bias[b][h]) * vvec[h], reduce over the block's 128 h
    f32x4 bi[4], vv[4];
#pragma unroll
    for (int mt = 0; mt < 4; ++mt) {
        int h = m0 + wi * 64 + mt * 16 + quad * 4;
        bi[mt] = *(const f32x4*)&bias[b * 512 + h];
        vv[mt] = *(const f32x4*)&vvec[h];
    }
#pragma unroll
    for (int nt = 0; nt < 4; ++nt) {
        float part = 0.f;
#pragma unroll
        for (int mt = 0; mt < 4; ++mt)
#pragma unroll
            for (int r = 0; r < 4; r++)
                part += tanh_fast(acc[mt][nt][r] + bi[mt][r]) * vv[mt][r];
        part += __shfl_down(part, 32);
        part += __shfl_down(part, 16);
        if (lane < 16) {
            int s = n0 + wj * 64 + nt * 16 + col;
            atomicAdd(&outAcc[b * 512 + s], part);
        }
    }
}

// ---------------- softmax over s (per b) ----------------
__global__ void softmax512(const float* __restrict__ sc, float* __restrict__ attn) {
    int b = blockIdx.x, t = threadIdx.x, lane = t & 63, w = t >> 6;
    __shared__ float sm[4];
    float v0 = sc[b * 512 + t], v1 = sc[b * 512 + 256 + t];
    float m = fmaxf(v0, v1);
    for (int d = 32; d; d >>= 1) m = fmaxf(m, __shfl_xor(m, d));
    if (lane == 0) sm[w] = m;
    __syncthreads();
    m = fmaxf(fmaxf(sm[0], sm[1]), fmaxf(sm[2], sm[3]));
    float e0 = __expf(v0 - m), e1 = __expf(v1 - m);
    float s = e0 + e1;
    for (int d = 32; d; d >>= 1) s += __shfl_xor(s, d);
    __syncthreads();
    if (lane == 0) sm[w] = s;
    __syncthreads();
    s = sm[0] + sm[1] + sm[2] + sm[3];
    float inv = 1.f / s;
    attn[b * 512 + t] = e0 * inv;
    attn[b * 512 + 256 + t] = e1 * inv;
}

// ---------------- context = attn @ static^T (per b) ----------------
__global__ __launch_bounds__(256) void context_kernel(
    const float* __restrict__ st, const float* __restrict__ attn,
    float* __restrict__ ctx, unsigned short* __restrict__ ctxbf) {
    int b = blockIdx.y, hq = blockIdx.x;
    int lane = threadIdx.x & 63, w = threadIdx.x >> 6;
    const float* ap = attn + b * 512 + lane * 8;
    f32x4 a0 = *(const f32x4*)ap, a1 = *(const f32x4*)(ap + 4);
    for (int i = 0; i < 32; i++) {
        int h = hq * 128 + w * 32 + i;
        const float* row = st + ((size_t)b * 512 + h) * 512 + lane * 8;
        f32x4 r0 = *(const f32x4*)row, r1 = *(const f32x4*)(row + 4);
        float sum = r0[0] * a0[0] + r0[1] * a0[1] + r0[2] * a0[2] + r0[3] * a0[3]
                  + r1[0] * a1[0] + r1[1] * a1[1] + r1[2] * a1[2] + r1[3] * a1[3];
#pragma unroll
        for (int d = 32; d; d >>= 1) sum += __shfl_down(sum, d);
        if (lane == 0) { ctx[b * 512 + h] = sum; ctxbf[b * 512 + h] = f2bf(sum); }
    }
}

extern "C" void kernel_launch(void* const* d_in, const int* in_sizes, int n_in,
                              void* d_out, int out_size, void* d_ws, size_t ws_size,
                              hipStream_t stream) {
    const float* st    = (const float*)d_in[0];
    const float* dy    = (const float*)d_in[1];
    const float* lo    = (const float*)d_in[2];
    const float* lh    = (const float*)d_in[3];
    const float* embW  = (const float*)d_in[4];
    const float* embb  = (const float*)d_in[5];
    const float* gWih  = (const float*)d_in[6];
    const float* gWhh  = (const float*)d_in[7];
    const float* bih   = (const float*)d_in[8];
    const float* bhh   = (const float*)d_in[9];
    const float* attnv = (const float*)d_in[10];
    const float* attnW = (const float*)d_in[11];
    const float* decv  = (const float*)d_in[12];
    const float* decW  = (const float*)d_in[13];
    float* outp = (float*)d_out;            // [B,S] pointer logits
    float* hiddenp = outp + 131072;         // [1,B,H] new hidden

    const size_t NEED = 281018368ULL;
    if (ws_size < NEED) {
        fill_sentinel<<<1024, 256, 0, stream>>>((float*)d_out, out_size);
        return;
    }
    char* ws = (char*)d_ws;
    unsigned short* stT = (unsigned short*)(ws);
    unsigned short* dyT = (unsigned short*)(ws + 134217728);
    char* s0 = ws + 268435456;
    unsigned short* Wab  = (unsigned short*)(s0);
    unsigned short* Wd1  = (unsigned short*)(s0 + 1048576);
    unsigned short* Wih  = (unsigned short*)(s0 + 1572864);
    unsigned short* Whh  = (unsigned short*)(s0 + 3145728);
    unsigned short* Wc   = (unsigned short*)(s0 + 4718592);
    unsigned short* Wd2  = (unsigned short*)(s0 + 5242880);
    unsigned short* xbf  = (unsigned short*)(s0 + 5767168);
    unsigned short* hbf  = (unsigned short*)(s0 + 6029312);
    unsigned short* hnbf = (unsigned short*)(s0 + 6291456);
    unsigned short* ctxbf= (unsigned short*)(s0 + 6553600);
    float* gx     = (float*)(s0 + 6815744);
    float* gh     = (float*)(s0 + 8388608);
    float* hc     = (float*)(s0 + 9961472);
    float* cd     = (float*)(s0 + 10485760);
    float* scores = (float*)(s0 + 11010048);
    float* attn   = (float*)(s0 + 11534336);
    float* ctx    = (float*)(s0 + 12058624);

    zero_kernel<<<512, 256, 0, stream>>>(scores, outp);
    prep_misc<<<12288, 256, 0, stream>>>(attnW, decW, gWih, gWhh, lo, embW, embb, lh,
                                         Wab, Wd1, Wih, Whh, Wc, Wd2, xbf, hbf);
    transpose_cast<<<dim3(64, 256, 2), 256, 0, stream>>>(st, dy, stT, dyT);
    gemm_nt_small<<<24, 256, 0, stream>>>(Wih, 512, xbf, 512, gx, 1536, 1536);
    gemm_nt_small<<<24, 256, 0, stream>>>(Whh, 512, hbf, 512, gh, 1536, 1536);
    gru_gates<<<512, 256, 0, stream>>>(gx, gh, lh, bih, bhh, hiddenp, hnbf);
    gemm_nt_small<<<8, 256, 0, stream>>>(Wc, 512, hnbf, 512, hc, 512, 512);
    big_gemm<<<4096, 256, 0, stream>>>(Wab, 1024, stT, dyT, 8, 16, hc, attnv, scores);
    softmax512<<<256, 256, 0, stream>>>(scores, attn);
    context_kernel<<<dim3(4, 256), 256, 0, stream>>>(st, attn, ctx, ctxbf);
    gemm_nt_small<<<8, 256, 0, stream>>>(Wd2, 512, ctxbf, 512, cd, 512, 512);
    big_gemm<<<4096, 256, 0, stream>>>(Wd1, 512, stT, stT, 8, 8, cd, decv, outp);
}

// Round 4
// 1019.313 us; speedup vs baseline: 1.1827x; 1.0499x over previous
//
#include <hip/hip_runtime.h>
#include <hip/hip_bf16.h>
#include <stdint.h>

// Decoder: B=256, H=512, S=512, O=2.
// Pipeline:
//  zero -> prep_misc (weight casts, embedding) -> transpose_cast (enc -> bf16 [b][s][k])
//  -> gemm gx, gh -> GRU gates (writes hidden out) -> gemm hc
//  -> big_gemm K1 (scores = sum_h v*tanh(Wa@st + Wb@dy + hc))  [K=1024 fused]
//  -> softmax -> context -> gemm cd
//  -> big_gemm K4 (outputs = sum_h dec_v*tanh(Wd1@st + cd))

typedef __attribute__((ext_vector_type(8))) short short8;
typedef __attribute__((ext_vector_type(4))) float f32x4;

__device__ __forceinline__ unsigned short f2bf(float f) {
    __hip_bfloat16 h = __float2bfloat16(f);
    return *reinterpret_cast<unsigned short*>(&h);
}
__device__ __forceinline__ float sigm(float x) { return 1.f / (1.f + __expf(-x)); }
__device__ __forceinline__ float tanh_fast(float x) {
    float e = __expf(2.f * x);
    return 1.f - 2.f / (e + 1.f);
}

// ---------------- tiny utility kernels ----------------
__global__ void zero_kernel(float* scores, float* outp) {
    int i = blockIdx.x * 256 + threadIdx.x;
    if (i < 131072) { scores[i] = 0.f; outp[i] = 0.f; }
}

__global__ void fill_sentinel(float* p, int n) {
    int i = blockIdx.x * 256 + threadIdx.x;
    if (i < n) p[i] = 12345.0f;
}

// weight casts + embedding + h cast. Flat-id ladder. 3,145,728 elems -> 12288 blocks.
__global__ void prep_misc(const float* __restrict__ attn_W, const float* __restrict__ dec_W,
                          const float* __restrict__ gWih, const float* __restrict__ gWhh,
                          const float* __restrict__ lo, const float* __restrict__ embW,
                          const float* __restrict__ embb, const float* __restrict__ lh,
                          unsigned short* Wab, unsigned short* Wd1,
                          unsigned short* Wih, unsigned short* Whh,
                          unsigned short* Wc, unsigned short* Wd2,
                          unsigned short* xbf, unsigned short* hbf) {
    int i = blockIdx.x * 256 + threadIdx.x;
    if (i < 786432) { Wih[i] = f2bf(gWih[i]); return; } i -= 786432;
    if (i < 786432) { Whh[i] = f2bf(gWhh[i]); return; } i -= 786432;
    if (i < 524288) { int m = i >> 10, k = i & 1023; Wab[i] = f2bf(attn_W[m * 1536 + k]); return; } i -= 524288;
    if (i < 262144) { int m = i >> 9, k = i & 511; Wc[i]  = f2bf(attn_W[m * 1536 + 1024 + k]); return; } i -= 262144;
    if (i < 262144) { int m = i >> 9, k = i & 511; Wd1[i] = f2bf(dec_W[m * 1024 + k]); return; } i -= 262144;
    if (i < 262144) { int m = i >> 9, k = i & 511; Wd2[i] = f2bf(dec_W[m * 1024 + 512 + k]); return; } i -= 262144;
    if (i < 131072) { int b = i >> 9, j = i & 511;
        float v = lo[b * 2] * embW[j * 2] + lo[b * 2 + 1] * embW[j * 2 + 1] + embb[j];
        xbf[i] = f2bf(v); return; } i -= 131072;
    if (i < 131072) { hbf[i] = f2bf(lh[i]); return; }
}

// enc [b][k][s] fp32 -> [b][s][k] bf16, LDS-tiled 64x64 transpose.
// Phase 1: float4 loads coalesced along s -> LDS [64][65] fp32 (pad 65 -> 2-way bank alias, free).
// Phase 2: gather 8 fp32 along k (2-way alias, free), cvt bf16, store contiguous 16B short8.
// Lanes 0..7 of phase-2 cover 128 contiguous output bytes -> full 64B-line coverage, no RMW.
__global__ __launch_bounds__(256) void transpose_cast(
    const float* __restrict__ st, const float* __restrict__ dy,
    unsigned short* __restrict__ stT, unsigned short* __restrict__ dyT) {
    __shared__ float tile[64 * 65];
    const int b = blockIdx.y;
    const int tx = blockIdx.x;                 // 0..63
    const int k0 = (tx & 7) * 64, s0 = (tx >> 3) * 64;
    const float* src = (blockIdx.z ? dy : st) + (size_t)b * 262144;
    unsigned short* dst = (blockIdx.z ? dyT : stT) + (size_t)b * 262144;
    const int t = threadIdx.x;
    const int sl = (t & 15) * 4, kl = t >> 4;  // kl 0..15
#pragma unroll
    for (int j = 0; j < 4; j++) {
        int k = kl + 16 * j;
        f32x4 v = *(const f32x4*)(src + (size_t)(k0 + k) * 512 + s0 + sl);
        tile[k * 65 + sl + 0] = v[0];
        tile[k * 65 + sl + 1] = v[1];
        tile[k * 65 + sl + 2] = v[2];
        tile[k * 65 + sl + 3] = v[3];
    }
    __syncthreads();
#pragma unroll
    for (int i = 0; i < 2; i++) {
        int idx = t + i * 256;
        int s = idx >> 3, kg = idx & 7;
        short8 o;
#pragma unroll
        for (int e = 0; e < 8; e++)
            o[e] = (short)f2bf(tile[(kg * 8 + e) * 65 + s]);
        *(short8*)(dst + (size_t)(s0 + s) * 512 + k0 + kg * 8) = o;
    }
}

// ---------------- small LDS-free MFMA GEMM ----------------
// D[n*ldd + m] = sum_k A[m][k]*B[n][k], K=512, N=256 fixed. 64x64 tile per wave.
__global__ __launch_bounds__(256) void gemm_nt_small(
    const unsigned short* __restrict__ A, int lda,
    const unsigned short* __restrict__ Bm, int ldb,
    float* __restrict__ D, int ldd, int Mdim) {
    int w = blockIdx.x * 4 + (threadIdx.x >> 6);
    int lane = threadIdx.x & 63;
    int mb = w >> 2, nbk = w & 3;   // N=256 -> 4 n-blocks
    if (mb >= (Mdim >> 6)) return;
    int m0 = mb * 64, n0 = nbk * 64;
    int col = lane & 15, quad = lane >> 4;
    f32x4 acc[4][4] = {};
    for (int k0 = 0; k0 < 512; k0 += 32) {
        short8 af[4], bfr[4];
#pragma unroll
        for (int t = 0; t < 4; t++)
            af[t] = *(const short8*)(A + (size_t)(m0 + t * 16 + col) * lda + k0 + quad * 8);
#pragma unroll
        for (int t = 0; t < 4; t++)
            bfr[t] = *(const short8*)(Bm + (size_t)(n0 + t * 16 + col) * ldb + k0 + quad * 8);
#pragma unroll
        for (int mt = 0; mt < 4; mt++)
#pragma unroll
            for (int nt = 0; nt < 4; nt++)
                acc[mt][nt] = __builtin_amdgcn_mfma_f32_16x16x32_bf16(af[mt], bfr[nt], acc[mt][nt], 0, 0, 0);
    }
#pragma unroll
    for (int mt = 0; mt < 4; mt++)
#pragma unroll
        for (int nt = 0; nt < 4; nt++) {
            int n = n0 + nt * 16 + col;
            int m = m0 + mt * 16 + quad * 4;
#pragma unroll
            for (int r = 0; r < 4; r++)
                D[(size_t)n * ldd + m + r] = acc[mt][nt][r];
        }
}

// ---------------- GRU gate fusion ----------------
__global__ void gru_gates(const float* __restrict__ gx, const float* __restrict__ gh,
                          const float* __restrict__ lh,
                          const float* __restrict__ bih, const float* __restrict__ bhh,
                          float* __restrict__ hidden_out, unsigned short* __restrict__ hnbf) {
    int i = blockIdx.x * 256 + threadIdx.x;  // 131072
    int b = i >> 9, j = i & 511;
    float xr = gx[b * 1536 + j] + bih[j];
    float xz = gx[b * 1536 + 512 + j] + bih[512 + j];
    float xn = gx[b * 1536 + 1024 + j] + bih[1024 + j];
    float hr = gh[b * 1536 + j] + bhh[j];
    float hz = gh[b * 1536 + 512 + j] + bhh[512 + j];
    float hn = gh[b * 1536 + 1024 + j] + bhh[1024 + j];
    float r = sigm(xr + hr), z = sigm(xz + hz);
    float n = tanh_fast(xn + r * hn);
    float h = (1.f - z) * n + z * lh[i];
    hidden_out[i] = h;
    hnbf[i] = f2bf(h);
}

// ---------------- big fused GEMM + tanh + v-dot reduce ----------------
// D[h][s] = sum_k A[h][k]*Benc[b][s][k] ; out[b][s] += sum_h vvec[h]*tanh(D + bias[b][h])
// 128x128 block (2x2 waves of 64x64), BK=64, global_load_lds staging,
// XOR source-swizzle (p = q ^ (row&7)) -> 2-way (free) LDS bank aliasing on frag reads.
// XCD swizzle (bijective, 4096%8==0): keeps B-tiles + weights L2-resident per XCD.
// 2-phase double-buffered pipeline (T3-min): issue STAGE(next) BEFORE compute(cur),
// single vmcnt(0)+barrier per K-step -> stage latency hides under 32 MFMA + 16 ds_read.
__global__ __launch_bounds__(256) void big_gemm(
    const unsigned short* __restrict__ A, int lda,
    const unsigned short* __restrict__ B1, const unsigned short* __restrict__ B2,
    int itersB1, int iters,
    const float* __restrict__ bias, const float* __restrict__ vvec,
    float* __restrict__ outAcc) {
    __shared__ __align__(16) unsigned short lds[32768];  // 2 x (16KB A + 16KB B) = 64KB
    const int wg0 = blockIdx.x;                       // 0..4095, XCD = wg0 % 8
    const int lin = (wg0 & 7) * 512 + (wg0 >> 3);     // bijective (4096 % 8 == 0)
    const int b = lin >> 4;
    const int m0 = (lin & 3) * 128, n0 = ((lin >> 2) & 3) * 128;
    const int tid = threadIdx.x, lane = tid & 63, w = tid >> 6;
    const int wi = w >> 1, wj = w & 1;
    const int col = lane & 15, quad = lane >> 4;
    f32x4 acc[4][4] = {};

    // staging slot geometry (per thread, fixed across iters)
    const int sbase = w * 256;                       // wave's 256-slot span
    auto stage = [&](int it, int buf) {
        const unsigned short* Bs; int kb;
        if (it < itersB1) { Bs = B1; kb = it * 64; } else { Bs = B2; kb = (it - itersB1) * 64; }
        const int ka = it * 64;
        unsigned short* ldsA = &lds[buf * 16384];
        unsigned short* ldsB = &lds[buf * 16384 + 8192];
#pragma unroll
        for (int i = 0; i < 4; i++) {
            int sb = sbase + i * 64;
            int slot = sb + lane;
            int row = slot >> 3, p = slot & 7, q = p ^ (row & 7);
            const unsigned short* g = A + (size_t)(m0 + row) * lda + (ka + q * 8);
            __builtin_amdgcn_global_load_lds((const __attribute__((address_space(1))) void*)g,
                                             (__attribute__((address_space(3))) void*)(&ldsA[sb * 8]), 16, 0, 0);
        }
        const unsigned short* Bbase = Bs + ((size_t)b * 512 + n0) * 512 + kb;
#pragma unroll
        for (int i = 0; i < 4; i++) {
            int sb = sbase + i * 64;
            int slot = sb + lane;
            int row = slot >> 3, p = slot & 7, q = p ^ (row & 7);
            const unsigned short* g = Bbase + (size_t)row * 512 + q * 8;
            __builtin_amdgcn_global_load_lds((const __attribute__((address_space(1))) void*)g,
                                             (__attribute__((address_space(3))) void*)(&ldsB[sb * 8]), 16, 0, 0);
        }
    };

    // prologue: fill buffer 0
    stage(0, 0);
    asm volatile("s_waitcnt vmcnt(0)" ::: "memory");
    __syncthreads();

    int cur = 0;
    for (int it = 0; it < iters; ++it) {
        // issue next tile's loads into the other buffer (in flight during compute)
        if (it + 1 < iters) stage(it + 1, cur ^ 1);
        const unsigned short* ldsA = &lds[cur * 16384];
        const unsigned short* ldsB = &lds[cur * 16384 + 8192];
#pragma unroll
        for (int ss = 0; ss < 2; ++ss) {
            short8 af[4], bfv[4];
#pragma unroll
            for (int t = 0; t < 4; t++) {
                int q = ss * 4 + quad;
                int m_loc = wi * 64 + t * 16 + col;
                int pa = q ^ (m_loc & 7);
                af[t] = *(const short8*)&ldsA[(m_loc * 8 + pa) * 8];
                int n_loc = wj * 64 + t * 16 + col;
                int pb = q ^ (n_loc & 7);
                bfv[t] = *(const short8*)&ldsB[(n_loc * 8 + pb) * 8];
            }
#pragma unroll
            for (int mt = 0; mt < 4; mt++)
#pragma unroll
                for (int nt = 0; nt < 4; nt++)
                    acc[mt][nt] = __builtin_amdgcn_mfma_f32_16x16x32_bf16(af[mt], bfv[nt], acc[mt][nt], 0, 0, 0);
        }
        // next tile's loads landed (they had the whole compute phase); all waves done
        // reading cur before it gets overwritten two iterations from now.
        asm volatile("s_waitcnt vmcnt(0)" ::: "memory");
        __syncthreads();
        cur ^= 1;
    }
    // epilogue: tanh(acc + bias[b][h]) * vvec[h], reduce over the block's 128 h
    f32x4 bi[4], vv[4];
#pragma unroll
    for (int mt = 0; mt < 4; ++mt) {
        int h = m0 + wi * 64 + mt * 16 + quad * 4;
        bi[mt] = *(const f32x4*)&bias[b * 512 + h];
        vv[mt] = *(const f32x4*)&vvec[h];
    }
#pragma unroll
    for (int nt = 0; nt < 4; ++nt) {
        float part = 0.f;
#pragma unroll
        for (int mt = 0; mt < 4; ++mt)
#pragma unroll
            for (int r = 0; r < 4; r++)
                part += tanh_fast(acc[mt][nt][r] + bi[mt][r]) * vv[mt][r];
        part += __shfl_down(part, 32);
        part += __shfl_down(part, 16);
        if (lane < 16) {
            int s = n0 + wj * 64 + nt * 16 + col;
            atomicAdd(&outAcc[b * 512 + s], part);
        }
    }
}

// ---------------- softmax over s (per b) ----------------
__global__ void softmax512(const float* __restrict__ sc, float* __restrict__ attn) {
    int b = blockIdx.x, t = threadIdx.x, lane = t & 63, w = t >> 6;
    __shared__ float sm[4];
    float v0 = sc[b * 512 + t], v1 = sc[b * 512 + 256 + t];
    float m = fmaxf(v0, v1);
    for (int d = 32; d; d >>= 1) m = fmaxf(m, __shfl_xor(m, d));
    if (lane == 0) sm[w] = m;
    __syncthreads();
    m = fmaxf(fmaxf(sm[0], sm[1]), fmaxf(sm[2], sm[3]));
    float e0 = __expf(v0 - m), e1 = __expf(v1 - m);
    float s = e0 + e1;
    for (int d = 32; d; d >>= 1) s += __shfl_xor(s, d);
    __syncthreads();
    if (lane == 0) sm[w] = s;
    __syncthreads();
    s = sm[0] + sm[1] + sm[2] + sm[3];
    float inv = 1.f / s;
    attn[b * 512 + t] = e0 * inv;
    attn[b * 512 + 256 + t] = e1 * inv;
}

// ---------------- context = attn @ static^T (per b) ----------------
__global__ __launch_bounds__(256) void context_kernel(
    const float* __restrict__ st, const float* __restrict__ attn,
    float* __restrict__ ctx, unsigned short* __restrict__ ctxbf) {
    int b = blockIdx.y, hq = blockIdx.x;
    int lane = threadIdx.x & 63, w = threadIdx.x >> 6;
    const float* ap = attn + b * 512 + lane * 8;
    f32x4 a0 = *(const f32x4*)ap, a1 = *(const f32x4*)(ap + 4);
    for (int i = 0; i < 32; i++) {
        int h = hq * 128 + w * 32 + i;
        const float* row = st + ((size_t)b * 512 + h) * 512 + lane * 8;
        f32x4 r0 = *(const f32x4*)row, r1 = *(const f32x4*)(row + 4);
        float sum = r0[0] * a0[0] + r0[1] * a0[1] + r0[2] * a0[2] + r0[3] * a0[3]
                  + r1[0] * a1[0] + r1[1] * a1[1] + r1[2] * a1[2] + r1[3] * a1[3];
#pragma unroll
        for (int d = 32; d; d >>= 1) sum += __shfl_down(sum, d);
        if (lane == 0) { ctx[b * 512 + h] = sum; ctxbf[b * 512 + h] = f2bf(sum); }
    }
}

extern "C" void kernel_launch(void* const* d_in, const int* in_sizes, int n_in,
                              void* d_out, int out_size, void* d_ws, size_t ws_size,
                              hipStream_t stream) {
    const float* st    = (const float*)d_in[0];
    const float* dy    = (const float*)d_in[1];
    const float* lo    = (const float*)d_in[2];
    const float* lh    = (const float*)d_in[3];
    const float* embW  = (const float*)d_in[4];
    const float* embb  = (const float*)d_in[5];
    const float* gWih  = (const float*)d_in[6];
    const float* gWhh  = (const float*)d_in[7];
    const float* bih   = (const float*)d_in[8];
    const float* bhh   = (const float*)d_in[9];
    const float* attnv = (const float*)d_in[10];
    const float* attnW = (const float*)d_in[11];
    const float* decv  = (const float*)d_in[12];
    const float* decW  = (const float*)d_in[13];
    float* outp = (float*)d_out;            // [B,S] pointer logits
    float* hiddenp = outp + 131072;         // [1,B,H] new hidden

    const size_t NEED = 281018368ULL;
    if (ws_size < NEED) {
        fill_sentinel<<<1024, 256, 0, stream>>>((float*)d_out, out_size);
        return;
    }
    char* ws = (char*)d_ws;
    unsigned short* stT = (unsigned short*)(ws);
    unsigned short* dyT = (unsigned short*)(ws + 134217728);
    char* s0 = ws + 268435456;
    unsigned short* Wab  = (unsigned short*)(s0);
    unsigned short* Wd1  = (unsigned short*)(s0 + 1048576);
    unsigned short* Wih  = (unsigned short*)(s0 + 1572864);
    unsigned short* Whh  = (unsigned short*)(s0 + 3145728);
    unsigned short* Wc   = (unsigned short*)(s0 + 4718592);
    unsigned short* Wd2  = (unsigned short*)(s0 + 5242880);
    unsigned short* xbf  = (unsigned short*)(s0 + 5767168);
    unsigned short* hbf  = (unsigned short*)(s0 + 6029312);
    unsigned short* hnbf = (unsigned short*)(s0 + 6291456);
    unsigned short* ctxbf= (unsigned short*)(s0 + 6553600);
    float* gx     = (float*)(s0 + 6815744);
    float* gh     = (float*)(s0 + 8388608);
    float* hc     = (float*)(s0 + 9961472);
    float* cd     = (float*)(s0 + 10485760);
    float* scores = (float*)(s0 + 11010048);
    float* attn   = (float*)(s0 + 11534336);
    float* ctx    = (float*)(s0 + 12058624);

    zero_kernel<<<512, 256, 0, stream>>>(scores, outp);
    prep_misc<<<12288, 256, 0, stream>>>(attnW, decW, gWih, gWhh, lo, embW, embb, lh,
                                         Wab, Wd1, Wih, Whh, Wc, Wd2, xbf, hbf);
    transpose_cast<<<dim3(64, 256, 2), 256, 0, stream>>>(st, dy, stT, dyT);
    gemm_nt_small<<<24, 256, 0, stream>>>(Wih, 512, xbf, 512, gx, 1536, 1536);
    gemm_nt_small<<<24, 256, 0, stream>>>(Whh, 512, hbf, 512, gh, 1536, 1536);
    gru_gates<<<512, 256, 0, stream>>>(gx, gh, lh, bih, bhh, hiddenp, hnbf);
    gemm_nt_small<<<8, 256, 0, stream>>>(Wc, 512, hnbf, 512, hc, 512, 512);
    big_gemm<<<4096, 256, 0, stream>>>(Wab, 1024, stT, dyT, 8, 16, hc, attnv, scores);
    softmax512<<<256, 256, 0, stream>>>(scores, attn);
    context_kernel<<<dim3(4, 256), 256, 0, stream>>>(st, attn, ctx, ctxbf);
    gemm_nt_small<<<8, 256, 0, stream>>>(Wd2, 512, ctxbf, 512, cd, 512, 512);
    big_gemm<<<4096, 256, 0, stream>>>(Wd1, 512, stT, stT, 8, 8, cd, decv, outp);
}